// Round 3
// baseline (1505.694 us; speedup 1.0000x reference)
//
#include <hip/hip_runtime.h>
#include <hip/hip_bf16.h>

#define BB 32
#define DCH 256
#define NG 64
#define NSTEP 31
#define CROW 1040   // total conv-output columns per (b, ch)

static const int h_lens[NSTEP] = {63,62,61,60,59,58,57,56,55,54,53,52,51,50,49,
                                  24,23,22,21,20,19,18,17,
                                  8,7,6,5,4,3,2,1};
static const int h_cb[NSTEP]   = {0,63,125,186,246,305,363,420,476,531,585,638,690,741,791,
                                  840,864,887,909,930,950,969,987,
                                  1004,1012,1019,1025,1030,1034,1037,1039};

__device__ __constant__ int d_cb[NSTEP] = {0,63,125,186,246,305,363,420,476,531,585,638,690,741,791,
                                           840,864,887,909,930,950,969,987,
                                           1004,1012,1019,1025,1030,1034,1037,1039};

// Generic conv1d-as-GEMM kernel.
// out[b, co, l] = bias[co] + sum_{ci,k} W[co*wcs + ci*K + k] * IN[b*ibs + ci*irs + (l0+l)*S + k]
// Block: 256 threads computes a [32 co x 64 l] tile for one b.
// grid = (B, co_tiles, l_tiles)
template<int K, int S>
__global__ __launch_bounds__(256)
void gconv(const float* __restrict__ IN, long ibs, int irs,
           const float* __restrict__ W, int wcs,
           const float* __restrict__ bias,
           float* __restrict__ OUT, long obs, int ors,
           int Lout)
{
    __shared__ float Xs[64][68];
    __shared__ float Ws[32][64*K + 1];
    const int t = threadIdx.x;
    const int b = blockIdx.x;
    const int cobase = blockIdx.y * 32;
    const int l0 = blockIdx.z * 64;
    const int Ltile = min(64, Lout - l0);
    const int Lin_tile = (Ltile - 1) * S + K;
    const int incol0 = l0 * S;

    const int cg = t & 7;    // 4 co's: cg*4 + c
    const int lg = t >> 3;   // 2 l's:  lg*2 + r

    float acc[4][2] = {{0.f,0.f},{0.f,0.f},{0.f,0.f},{0.f,0.f}};

    for (int cb = 0; cb < DCH; cb += 64) {
        // ---- stage X tile: [64 ci][Lin_tile cols]
        {
            const int cc = t & 15;
            const int cr = t >> 4;  // 0..15
            #pragma unroll
            for (int p = 0; p < 4; ++p) {
                const int ci = cr + p*16;
                const float* src = IN + (size_t)b*ibs + (size_t)(cb+ci)*irs + incol0;
                for (int c = cc; c < Lin_tile; c += 16)
                    Xs[ci][c] = src[c];
            }
        }
        // ---- stage W tile: [32 co][64*K]  (layout [co][ci*K+k], row pad +1)
        {
            const int kci = t & 63;
            const int coo = t >> 6;  // 0..3
            #pragma unroll
            for (int co = 0; co < 8; ++co) {
                const int cor = coo + co*4;
                const float* wsrc = W + (size_t)(cobase+cor)*wcs + cb*K;
                #pragma unroll
                for (int c = 0; c < K; ++c)
                    Ws[cor][kci + c*64] = wsrc[kci + c*64];
            }
        }
        __syncthreads();
        #pragma unroll 8
        for (int ci = 0; ci < 64; ++ci) {
            float xarr[(S==1) ? 4 : 5];
            if (S == 1) {
                const float2 xa = *(const float2*)&Xs[ci][lg*2];
                const float2 xb = *(const float2*)&Xs[ci][lg*2 + 2];
                xarr[0]=xa.x; xarr[1]=xa.y; xarr[2]=xb.x; xarr[3]=xb.y;
            } else {
                const int lxb = (lg*4 > 60) ? 60 : lg*4;   // clamp: OOB lanes discarded at store
                const float4 xq = *(const float4*)&Xs[ci][lxb];
                xarr[0]=xq.x; xarr[1]=xq.y; xarr[2]=xq.z; xarr[3]=xq.w;
                xarr[4]=Xs[ci][lxb+4];
            }
            #pragma unroll
            for (int k = 0; k < K; ++k) {
                const int kc = ci*K + k;
                const float w0 = Ws[cg*4+0][kc];
                const float w1 = Ws[cg*4+1][kc];
                const float w2 = Ws[cg*4+2][kc];
                const float w3 = Ws[cg*4+3][kc];
                #pragma unroll
                for (int r = 0; r < 2; ++r) {
                    const float x = xarr[(S==1) ? (r+k) : (2*r+k)];
                    acc[0][r] += w0*x;
                    acc[1][r] += w1*x;
                    acc[2][r] += w2*x;
                    acc[3][r] += w3*x;
                }
            }
        }
        __syncthreads();
    }
    #pragma unroll
    for (int c = 0; c < 4; ++c) {
        const int co = cobase + cg*4 + c;
        const float bv = bias ? bias[co] : 0.f;
        #pragma unroll
        for (int r = 0; r < 2; ++r) {
            const int l = lg*2 + r;
            if (l < Ltile)
                OUT[(size_t)b*obs + (size_t)co*ors + l0 + l] = acc[c][r] + bv;
        }
    }
}

// Final assembly:
// out[b,o,i,j] = vis_b[o]                                   (unset)
//              + P_l[b,o,i] + P_mx[b,o,i] + P_r[b,o,i]      (diag)
//              + P_l[b,o,i] + Q[b,o,q]    + P_r[b,o,j]      (set off-diag)
// P layout: [part(3)][b][o][64], Q layout: [b][o][1040]
__global__ __launch_bounds__(256)
void final_k(const float* __restrict__ P, const float* __restrict__ Qb,
             const float* __restrict__ vb, float* __restrict__ out)
{
    const int b = blockIdx.x >> 6;
    const int i = blockIdx.x & 63;
    const int t = threadIdx.x;
    const int j = t & 63;
    const int os = t >> 6;

    __shared__ int qidx[64];
    if (t < 64) {
        const int d = t - i;
        int v = -1;
        if (t == i) v = -2;
        else if (d >= 1 && d <= 15) v = d_cb[d-1] + i;
        else if (d >= 17 && d <= 31 && (d & 1) && !(i & 1)) v = d_cb[15 + ((d-17)>>1)] + (i>>1);
        else if (d >= 35 && d <= 63 && ((d-35)&3)==0 && !(i&3)) v = d_cb[23 + ((d-35)>>2)] + (i>>2);
        qidx[t] = v;
    }
    __syncthreads();
    const int q = qidx[j];

    for (int oc = 0; oc < 64; ++oc) {
        const int o = oc*4 + os;
        const float pl = P[(size_t)(b*256+o)*64 + i];
        const float pm = P[524288u + (size_t)(b*256+o)*64 + i];
        const float* pr = P + 1048576u + (size_t)(b*256+o)*64;
        const float vbv = vb[o];
        float v;
        if (q == -2)      v = pl + pm + pr[i] + vbv;
        else if (q >= 0)  v = pl + Qb[((size_t)b*256+o)*1040 + q] + pr[j] + vbv;
        else              v = vbv;
        out[(((size_t)b*256 + o)*64 + i)*64 + j] = v;
    }
}

extern "C" void kernel_launch(void* const* d_in, const int* in_sizes, int n_in,
                              void* d_out, int out_size, void* d_ws, size_t ws_size,
                              hipStream_t stream)
{
    const float* x   = (const float*)d_in[0];   // [32,256,64]
    const float* w2  = (const float*)d_in[1];   // [29,256,256,2]
    const float* b2  = (const float*)d_in[2];   // [29,256]
    const float* w3  = (const float*)d_in[3];   // [2,256,256,3]
    const float* b3  = (const float*)d_in[4];   // [2,256]
    const float* vw  = (const float*)d_in[5];   // [256,768]
    const float* vb  = (const float*)d_in[6];   // [256]
    float* out = (float*)d_out;                 // [32,256,64,64]

    float* C = (float*)d_ws;                    // [32][256][1040]  34.1 MB
    float* Q = C + (size_t)BB*DCH*CROW;         // [32][256][1040]  34.1 MB
    float* P = Q + (size_t)BB*DCH*CROW;         // [3][32][256][64]  6.3 MB

    const long cbs = (long)DCH*CROW;   // per-b stride in C/Q
    const long xbs = (long)DCH*NG;     // per-b stride in x / P-part

    // projections P_l (part0: Wl·x), P_mx (part1: Wm·x), P_r (part2: Wr·x)
    for (int part = 0; part < 3; ++part) {
        gconv<1,1><<<dim3(BB,8,1),256,0,stream>>>(
            x, xbs, NG,
            vw + part*256, 768, nullptr,
            P + (size_t)part*BB*DCH*NG, xbs, NG, NG);
    }

    // sequential conv chain; step t reads C segment t-1 (or x), writes segment t
    int i2 = 0, i3 = 0;
    for (int t = 0; t < NSTEP; ++t) {
        const int ks = (t==15 || t==23) ? 3 : 2;
        const int Lout = h_lens[t];
        const float* IN = (t==0) ? x : (const float*)(C + h_cb[t-1]);
        const long  ibs = (t==0) ? xbs : cbs;
        const int   irs = (t==0) ? NG : CROW;
        float* O = C + h_cb[t];
        if (ks == 2) {
            gconv<2,1><<<dim3(BB,8,1),256,0,stream>>>(
                IN, ibs, irs,
                w2 + (size_t)i2*DCH*DCH*2, DCH*2, b2 + i2*DCH,
                O, cbs, CROW, Lout);
            ++i2;
        } else {
            gconv<3,2><<<dim3(BB,8,1),256,0,stream>>>(
                IN, ibs, irs,
                w3 + (size_t)i3*DCH*DCH*3, DCH*3, b3 + i3*DCH,
                O, cbs, CROW, Lout);
            ++i3;
        }
    }

    // Q = Wm · C over all 1040 columns
    gconv<1,1><<<dim3(BB,8,17),256,0,stream>>>(
        C, cbs, CROW,
        vw + 256, 768, nullptr,
        Q, cbs, CROW, CROW);

    // final gather + write
    final_k<<<dim3(BB*NG),256,0,stream>>>(P, Q, vb, out);
}

// Round 4
// 625.698 us; speedup vs baseline: 2.4064x; 2.4064x over previous
//
#include <hip/hip_runtime.h>

#define BB 32
#define NSTEP 31
#define CROW 1040
#define CB_STRIDE 266240L   // 1040*256 elems per b (Cb bf16 / Q f32)
#define XB_STRIDE 16384L    // 64*256 elems per b (xb)
#define PPART 524288L       // 32*64*256 elems per part (P)

static const int h_lens[NSTEP] = {63,62,61,60,59,58,57,56,55,54,53,52,51,50,49,
                                  24,23,22,21,20,19,18,17,
                                  8,7,6,5,4,3,2,1};
static const int h_cb[NSTEP]   = {0,63,125,186,246,305,363,420,476,531,585,638,690,741,791,
                                  840,864,887,909,930,950,969,987,
                                  1004,1012,1019,1025,1030,1034,1037,1039};

__device__ __constant__ int d_cb[NSTEP] = {0,63,125,186,246,305,363,420,476,531,585,638,690,741,791,
                                           840,864,887,909,930,950,969,987,
                                           1004,1012,1019,1025,1030,1034,1037,1039};

typedef short v8s __attribute__((ext_vector_type(8)));
typedef float v4f __attribute__((ext_vector_type(4)));

__device__ __forceinline__ unsigned short rne_bf16(float f) {
    unsigned int u = __float_as_uint(f);
    u = (u + 0x7FFFu + ((u >> 16) & 1u)) >> 16;
    return (unsigned short)u;
}

// One-shot dtype/layout prep:
//  xb [32][64][256]  bf16  <- x[32][256][64]        (time-major transpose)
//  w2t[29*256][2][256] bf16 <- w2[29*256][256][2]   (k-major transpose)
//  w3t[2*256][3][256]  bf16 <- w3[2*256][256][3]
//  vwb[256][768]       bf16 <- vw                    (plain cast)
__global__ __launch_bounds__(256)
void prep(const float* __restrict__ x, const float* __restrict__ w2,
          const float* __restrict__ w3, const float* __restrict__ vw,
          unsigned short* __restrict__ xb, unsigned short* __restrict__ w2t,
          unsigned short* __restrict__ w3t, unsigned short* __restrict__ vwb)
{
    long idx = (long)blockIdx.x * 256 + threadIdx.x;
    if (idx < 524288) {                       // xb
        const int ci = idx & 255, l = (idx >> 8) & 63, b = (int)(idx >> 14);
        xb[idx] = rne_bf16(x[((long)b << 14) + ((long)ci << 6) + l]);
        return;
    }
    idx -= 524288;
    if (idx < 3801088) {                      // w2t
        const int ci = idx & 255, k = (idx >> 8) & 1; const long row = idx >> 9;
        w2t[idx] = rne_bf16(w2[row * 512 + ci * 2 + k]);
        return;
    }
    idx -= 3801088;
    if (idx < 393216) {                       // w3t
        const int ci = idx & 255; const long r = idx >> 8;
        const int k = (int)(r % 3); const long row = r / 3;
        w3t[idx] = rne_bf16(w3[row * 768 + ci * 3 + k]);
        return;
    }
    idx -= 393216;
    if (idx < 196608) vwb[idx] = rne_bf16(vw[idx]);
}

// MFMA GEMM: D[m][n] = sum_k A[m][acol+ k]*Bcol[k][n] (+bias[m])
// m = co/o (0..255 per M-tile), n = l*32 + b (b-minor), k = k_conv*256 + ci.
// B is time-major activations [32][rows][256] bf16: column (b,l) K-slice is
// LINEAR in memory (row stride 512B == 256-elem K-block) -> one 16B load/frag.
// OMODE 0: bf16 out Cb[b][orow0+l][m] + bias
// OMODE 1: f32  out Q [b][l][m]          (m contiguous, float4)
// OMODE 2: f32  out P [p][b][m][l]       (p = blockIdx.y, proj)
template<int KC, int S, int OMODE>
__global__ __launch_bounds__(256)
void mg(const unsigned short* __restrict__ A, int arow, int acol0,
        const unsigned short* __restrict__ B, long bbstr, int brow0,
        const float* __restrict__ bias,
        void* __restrict__ OUT, int orow0)
{
    const int lane = threadIdx.x & 63;
    const int wave = threadIdx.x >> 6;
    const int nl = lane & 15, g = lane >> 4;
    const int n = blockIdx.x * 16 + nl;
    const int b = n & 31;
    const int l = n >> 5;
    const int p = blockIdx.y;

    const unsigned short* Ab = A + (size_t)(wave * 64 + nl) * arow + acol0 + p * 256 + g * 8;
    const unsigned short* Bb = B + (size_t)b * bbstr + (size_t)(brow0 + l * S) * 256 + g * 8;

    v4f acc[4] = {};
    #pragma unroll
    for (int k = 0; k < KC * 8; ++k) {
        const v8s bf = *(const v8s*)(Bb + k * 32);
        #pragma unroll
        for (int mf = 0; mf < 4; ++mf) {
            const v8s af = *(const v8s*)(Ab + (size_t)mf * 16 * arow + k * 32);
            acc[mf] = __builtin_amdgcn_mfma_f32_16x16x32_bf16(af, bf, acc[mf], 0, 0, 0);
        }
    }

    #pragma unroll
    for (int mf = 0; mf < 4; ++mf) {
        const int m0 = wave * 64 + mf * 16 + g * 4;   // rows m0..m0+3 (reg r)
        if constexpr (OMODE == 0) {
            const float4 bv = *(const float4*)(bias + m0);
            ushort4 pk;
            pk.x = rne_bf16(acc[mf][0] + bv.x);
            pk.y = rne_bf16(acc[mf][1] + bv.y);
            pk.z = rne_bf16(acc[mf][2] + bv.z);
            pk.w = rne_bf16(acc[mf][3] + bv.w);
            *(ushort4*)((unsigned short*)OUT + (size_t)b * CB_STRIDE + (size_t)(orow0 + l) * 256 + m0) = pk;
        } else if constexpr (OMODE == 1) {
            *(v4f*)((float*)OUT + (size_t)b * CB_STRIDE + (size_t)l * 256 + m0) = acc[mf];
        } else {
            float* Po = (float*)OUT + (size_t)p * PPART + (size_t)b * XB_STRIDE + l;
            #pragma unroll
            for (int r = 0; r < 4; ++r) Po[(size_t)(m0 + r) * 64] = acc[mf][r];
        }
    }
}

// out[b,o,i,j] = vis_b[o]                          (unset)
//             + Pl[b,o,i]+Pm[b,o,i]+Pr[b,o,i]      (diag)
//             + Pl[b,o,i]+Q[b,q,o]+Pr[b,o,j]       (set off-diag)
__global__ __launch_bounds__(256)
void final_k(const float* __restrict__ P, const float* __restrict__ Qb,
             const float* __restrict__ vb, float* __restrict__ out)
{
    const int b = blockIdx.x >> 6;
    const int i = blockIdx.x & 63;
    const int t = threadIdx.x;
    const int j = t & 63;
    const int os = t >> 6;

    __shared__ int qidx[64];
    if (t < 64) {
        const int d = t - i;
        int v = -1;
        if (t == i) v = -2;
        else if (d >= 1 && d <= 15) v = d_cb[d-1] + i;
        else if (d >= 17 && d <= 31 && (d & 1) && !(i & 1)) v = d_cb[15 + ((d-17)>>1)] + (i>>1);
        else if (d >= 35 && d <= 63 && ((d-35)&3)==0 && !(i&3)) v = d_cb[23 + ((d-35)>>2)] + (i>>2);
        qidx[t] = v;
    }
    __syncthreads();
    const int q = qidx[j];

    for (int oc = 0; oc < 64; ++oc) {
        const int o = oc * 4 + os;
        const float pl = P[(size_t)(b * 256 + o) * 64 + i];
        const float pm = P[524288u + (size_t)(b * 256 + o) * 64 + i];
        const float* pr = P + 1048576u + (size_t)(b * 256 + o) * 64;
        const float vbv = vb[o];
        float v;
        if (q == -2)      v = pl + pm + pr[i] + vbv;
        else if (q >= 0)  v = pl + Qb[(size_t)b * CB_STRIDE + (size_t)q * 256 + o] + pr[j] + vbv;
        else              v = vbv;
        out[(((size_t)b * 256 + o) * 64 + i) * 64 + j] = v;
    }
}

extern "C" void kernel_launch(void* const* d_in, const int* in_sizes, int n_in,
                              void* d_out, int out_size, void* d_ws, size_t ws_size,
                              hipStream_t stream)
{
    const float* x   = (const float*)d_in[0];
    const float* w2  = (const float*)d_in[1];
    const float* b2  = (const float*)d_in[2];
    const float* w3  = (const float*)d_in[3];
    const float* b3  = (const float*)d_in[4];
    const float* vw  = (const float*)d_in[5];
    const float* vb  = (const float*)d_in[6];
    float* out = (float*)d_out;

    // workspace carve-up (bytes): Q f32 34.08M | P f32 6.29M | Cb bf16 17.04M
    //                           | xb 1.05M | w2t 7.60M | w3t 0.79M | vwb 0.39M = 67.2 MB
    char* w = (char*)d_ws;
    float*          Qf  = (float*)w;                  w += (size_t)BB * CB_STRIDE * 4;
    float*          P   = (float*)w;                  w += (size_t)3 * PPART * 4;
    unsigned short* Cb  = (unsigned short*)w;         w += (size_t)BB * CB_STRIDE * 2;
    unsigned short* xb  = (unsigned short*)w;         w += (size_t)BB * XB_STRIDE * 2;
    unsigned short* w2t = (unsigned short*)w;         w += (size_t)29 * 256 * 512 * 2;
    unsigned short* w3t = (unsigned short*)w;         w += (size_t)2 * 256 * 768 * 2;
    unsigned short* vwb = (unsigned short*)w;

    // 1) dtype/layout prep (4,915,200 elems)
    prep<<<dim3(19200), 256, 0, stream>>>(x, w2, w3, vw, xb, w2t, w3t, vwb);

    // 2) projections P[p][b][o][i], p=0,1,2 <- vw slices * x
    mg<1,1,2><<<dim3(128, 3), 256, 0, stream>>>(vwb, 768, 0, xb, XB_STRIDE, 0, nullptr, P, 0);

    // 3) sequential conv chain (bf16 MFMA), activations time-major in Cb
    int i2 = 0, i3 = 0;
    for (int t = 0; t < NSTEP; ++t) {
        const int L = h_lens[t];
        const unsigned short* Bsrc = (t == 0) ? xb : Cb;
        const long bst  = (t == 0) ? XB_STRIDE : CB_STRIDE;
        const int brow0 = (t == 0) ? 0 : h_cb[t-1];
        if (t == 15 || t == 23) {
            mg<3,2,0><<<dim3(2*L, 1), 256, 0, stream>>>(
                w3t + (size_t)i3 * 196608, 768, 0, Bsrc, bst, brow0,
                b3 + i3 * 256, Cb, h_cb[t]);
            ++i3;
        } else {
            mg<2,1,0><<<dim3(2*L, 1), 256, 0, stream>>>(
                w2t + (size_t)i2 * 131072, 512, 0, Bsrc, bst, brow0,
                b2 + i2 * 256, Cb, h_cb[t]);
            ++i2;
        }
    }

    // 4) Q[b][q][o] = Wm * C  (N = 32*1040)
    mg<1,1,1><<<dim3(2080, 1), 256, 0, stream>>>(vwb, 768, 256, Cb, CB_STRIDE, 0, nullptr, Qf, 0);

    // 5) gather + assemble output
    final_k<<<dim3(BB * 64), 256, 0, stream>>>(P, Qf, vb, out);
}